// Round 1
// baseline (40.310 us; speedup 1.0000x reference)
//
#include <hip/hip_runtime.h>

#define BB 32
#define TT 1024
#define T_OUT 4096
#define DD 384
#define F4_PER_ROW (DD / 4)   // 96

// Kernel 1: one block per batch. Computes masked durations, total (with the
// total==0 -> d=valid fallback), exclusive prefix sum, and scatters the source
// token index for every real output frame into src_idx; pad frames get -1.
__global__ __launch_bounds__(256) void build_src_kernel(
    const int* __restrict__ durations,
    const int* __restrict__ input_lengths,
    int* __restrict__ src_idx) {
  const int b = blockIdx.x;
  const int tid = threadIdx.x;
  const int len = input_lengths[b];
  const int t0 = tid * 4;

  // Load 4 durations per thread (T=1024 / 256 threads), mask past len.
  const int4 dv = *reinterpret_cast<const int4*>(&durations[b * TT + t0]);
  int d[4] = {dv.x, dv.y, dv.z, dv.w};
#pragma unroll
  for (int i = 0; i < 4; ++i)
    if (t0 + i >= len) d[i] = 0;

  int s = d[0] + d[1] + d[2] + d[3];

  // Block-wide total via wave reduce + LDS.
  const int lane = tid & 63;
  const int wid = tid >> 6;
  __shared__ int wred[4];
  __shared__ int wsum[4];
  int r = s;
#pragma unroll
  for (int off = 32; off > 0; off >>= 1) r += __shfl_xor(r, off);
  if (lane == 0) wred[wid] = r;
  __syncthreads();
  int total = wred[0] + wred[1] + wred[2] + wred[3];

  // Reference fallback: if all masked durations are zero, d = valid (1s).
  if (total == 0) {
#pragma unroll
    for (int i = 0; i < 4; ++i) d[i] = (t0 + i < len) ? 1 : 0;
    s = d[0] + d[1] + d[2] + d[3];
    total = len;  // len in [0, T); count of valid tokens
  }

  // Inclusive wave scan of per-thread sums, then cross-wave offset.
  int v = s;
#pragma unroll
  for (int off = 1; off < 64; off <<= 1) {
    int u = __shfl_up(v, off);
    if (lane >= off) v += u;
  }
  if (lane == 63) wsum[wid] = v;
  __syncthreads();
  int wpre = 0;
#pragma unroll
  for (int w = 0; w < 4; ++w)
    if (w < wid) wpre += wsum[w];
  int run = wpre + v - s;  // exclusive prefix over this thread's 4 tokens

  // Scatter: token t owns output frames [run, run + d[i])
  int* base = src_idx + b * T_OUT;
#pragma unroll
  for (int i = 0; i < 4; ++i) {
    for (int k = 0; k < d[i]; ++k) base[run + k] = t0 + i;
    run += d[i];
  }

  // Pad tail with -1.
  for (int k = total + tid; k < T_OUT; k += 256) base[k] = -1;
}

// Kernel 2: streaming gather-copy. One thread per float4 of the output.
// Consecutive threads -> consecutive addresses for both read and write.
__global__ __launch_bounds__(256) void gather_copy_kernel(
    const float4* __restrict__ xs,
    const int* __restrict__ src_idx,
    float4* __restrict__ out,
    int n_elem) {
  const int idx = blockIdx.x * blockDim.x + threadIdx.x;
  if (idx >= n_elem) return;
  const unsigned uidx = (unsigned)idx;
  const unsigned frame = uidx / F4_PER_ROW;        // magic-mul, cheap
  const unsigned lane = uidx - frame * F4_PER_ROW; // position within row
  const int src = src_idx[frame];
  const unsigned b = frame >> 12;                  // T_OUT = 4096
  float4 val = make_float4(0.f, 0.f, 0.f, 0.f);
  if (src >= 0) {
    val = xs[((b << 10) + (unsigned)src) * F4_PER_ROW + lane];  // T = 1024
  }
  out[idx] = val;
}

extern "C" void kernel_launch(void* const* d_in, const int* in_sizes, int n_in,
                              void* d_out, int out_size, void* d_ws, size_t ws_size,
                              hipStream_t stream) {
  const float* xs = (const float*)d_in[0];
  const int* durations = (const int*)d_in[1];
  const int* input_lengths = (const int*)d_in[2];
  float* out = (float*)d_out;
  int* src_idx = (int*)d_ws;  // B * T_OUT * 4 B = 512 KB

  build_src_kernel<<<BB, 256, 0, stream>>>(durations, input_lengths, src_idx);

  const int n_elem = BB * T_OUT * F4_PER_ROW;  // 12,582,912 float4s
  gather_copy_kernel<<<(n_elem + 255) / 256, 256, 0, stream>>>(
      (const float4*)xs, src_idx, (float4*)out, n_elem);
}